// Round 10
// baseline (214.714 us; speedup 1.0000x reference)
//
#include <hip/hip_runtime.h>
#include <hip/hip_bf16.h>
#include <math.h>

typedef __bf16 bf16;
typedef __bf16 bf16x4 __attribute__((ext_vector_type(4)));
typedef __bf16 bf16x8 __attribute__((ext_vector_type(8)));
typedef float f32x4 __attribute__((ext_vector_type(4)));
typedef int i32x4 __attribute__((ext_vector_type(4)));

#define SEQ 2048
#define NHEADS 16
#define HDIM 64
#define DM 1024
#define QKVW 3072

__device__ __forceinline__ void gload_lds16(const void* g, void* l) {
  __builtin_amdgcn_global_load_lds(
      (const __attribute__((address_space(1))) unsigned int*)g,
      (__attribute__((address_space(3))) unsigned int*)l, 16, 0, 0);
}

// pack two f32 -> one dword of 2 bf16 (lo = a, hi = b)
__device__ __forceinline__ int pk2(float a, float b) {
  union { __bf16 h; unsigned short u; } ua, ub;
  ua.h = (__bf16)a; ub.h = (__bf16)b;
  return (int)ua.u | ((int)ub.u << 16);
}

// ---------------- prep: cvt | transpose wqkv | transpose wout | rope table --
__global__ __launch_bounds__(256) void prep(
    const float* __restrict__ hidden, const float* __restrict__ w_qkv,
    const float* __restrict__ w_out, const int* __restrict__ pos,
    bf16* __restrict__ hid_bf, bf16* __restrict__ wqkvT,
    bf16* __restrict__ woutT, float2* __restrict__ tbl) {
  __shared__ float tile[64][65];
  int idx = blockIdx.x, tid = threadIdx.x;
  if (idx < 2048) {  // cvt f32->bf16, 8 elems/thread
    int i = (idx * 256 + tid) * 8;
    float4 a = *(const float4*)(hidden + i);
    float4 b = *(const float4*)(hidden + i + 4);
    bf16x8 o;
    o[0] = (bf16)a.x; o[1] = (bf16)a.y; o[2] = (bf16)a.z; o[3] = (bf16)a.w;
    o[4] = (bf16)b.x; o[5] = (bf16)b.y; o[6] = (bf16)b.z; o[7] = (bf16)b.w;
    *(bf16x8*)(hid_bf + i) = o;
  } else if (idx < 3072) {  // weight transposes f32 -> bf16^T
    const float* in; bf16* out; int R, C, t;
    if (idx < 2816) { t = idx - 2048; in = w_qkv; out = wqkvT; R = 1024; C = 3072; }
    else            { t = idx - 2816; in = w_out; out = woutT; R = 1024; C = 1024; }
    int nbx = C >> 6;
    int c0 = (t % nbx) * 64, r0 = (t / nbx) * 64;
    int col = tid & 63, rb = (tid >> 6) * 16;
#pragma unroll
    for (int i = 0; i < 16; ++i)
      tile[rb + i][col] = in[(size_t)(r0 + rb + i) * C + c0 + col];
    __syncthreads();
#pragma unroll
    for (int i = 0; i < 16; ++i)
      out[(size_t)(c0 + rb + i) * R + r0 + col] = (bf16)tile[col][rb + i];
  } else {  // rope table: tbl[m][pair] = (cos, sin)
    const float LN1E4 = 9.210340371976184f;
    int gi = (idx - 3072) * 256 + tid;  // 4096*32
    int m = gi >> 5, pr = gi & 31;
    int axis, d, iloc;
    if (pr < 10)      { axis = 0; d = 20; iloc = pr; }
    else if (pr < 20) { axis = 1; d = 20; iloc = pr - 10; }
    else              { axis = 2; d = 24; iloc = pr - 20; }
    int p = pos[m * 3 + axis];
    int pmax = (axis == 2) ? 7 : 31;
    p = p < 0 ? 0 : (p > pmax ? pmax : p);
    float invf = __expf(-((float)(2 * iloc) / (float)d) * LN1E4);
    float sn, cs;
    __sincosf((float)p * invf, &sn, &cs);
    tbl[gi] = make_float2(cs, sn);
  }
}

// ------- GEMM 128x128 with fused RoPE (Q|K cols) / V^T direct (V cols) ------
// Q|K (n0<2048): RoPE on the f32 accumulator before bf16 store (R9-verified).
// V (n0>=2048): MFMA operands SWAPPED in the K-loop -> tile computed
// transposed in registers (row=n=d, col=m=s); store to vT[bh][d][s] is then
// 16-lane-contiguous (32B segments) -- no scatter, zero extra instructions.
__global__ __launch_bounds__(256) void gemm_qkv(
    const bf16* __restrict__ A, const bf16* __restrict__ Bt,
    bf16* __restrict__ C, const float2* __restrict__ tbl,
    bf16* __restrict__ vT, int M, int N, int K) {
  __shared__ __align__(16) bf16 a_lds[128 * 32];
  __shared__ __align__(16) bf16 b_lds[128 * 32];
  int tid = threadIdx.x;
  int wave = tid >> 6, lane = tid & 63;
  int quad = lane >> 4, l15 = lane & 15;
  int wm = wave >> 1, wn = wave & 1;

  int flat = blockIdx.y * gridDim.x + blockIdx.x;
  int mband = gridDim.y >> 3;
  int xcd = flat & 7, sidx = flat >> 3;
  int m0 = (xcd * mband + (sidx % mband)) * 128;
  int n0 = (sidx / mband) * 128;
  bool vblk = (n0 >= 2048);

  f32x4 acc[4][4] = {};

  for (int kt = 0; kt < K; kt += 32) {
    __syncthreads();
#pragma unroll
    for (int call = 0; call < 2; ++call) {
      int chunk = call * 256 + tid;
      int row = chunk >> 2, cc = (chunk & 3) * 8;
      gload_lds16(A + (size_t)(m0 + row) * K + kt + cc,
                  (char*)a_lds + call * 4096 + wave * 1024);
      gload_lds16(Bt + (size_t)(n0 + row) * K + kt + cc,
                  (char*)b_lds + call * 4096 + wave * 1024);
    }
    __syncthreads();
    bf16x8 af[4], bfr[4];
#pragma unroll
    for (int i = 0; i < 4; ++i) {
      af[i]  = *(const bf16x8*)(a_lds + (wm * 64 + i * 16 + l15) * 32 + quad * 8);
      bfr[i] = *(const bf16x8*)(b_lds + (wn * 64 + i * 16 + l15) * 32 + quad * 8);
    }
    if (vblk) {  // swapped operands -> acc holds C^T (row=n, col=m)
#pragma unroll
      for (int mi = 0; mi < 4; ++mi)
#pragma unroll
        for (int ni = 0; ni < 4; ++ni)
          acc[mi][ni] = __builtin_amdgcn_mfma_f32_16x16x32_bf16(
              bfr[ni], af[mi], acc[mi][ni], 0, 0, 0);
    } else {
#pragma unroll
      for (int mi = 0; mi < 4; ++mi)
#pragma unroll
        for (int ni = 0; ni < 4; ++ni)
          acc[mi][ni] = __builtin_amdgcn_mfma_f32_16x16x32_bf16(
              af[mi], bfr[ni], acc[mi][ni], 0, 0, 0);
    }
  }

  if (vblk) {  // V: acc[mi][ni] is C^T tile; row n = 4*quad+r (d), col m = l15 (s)
    int b = m0 >> 11;  // block-uniform (m0 multiple of 128)
#pragma unroll
    for (int mi = 0; mi < 4; ++mi) {
      int scol = m0 + wm * 64 + mi * 16 + l15 - b * 2048;
#pragma unroll
      for (int ni = 0; ni < 4; ++ni) {
        int nb = n0 + wn * 64 + ni * 16 + 4 * quad;
#pragma unroll
        for (int r = 0; r < 4; ++r) {
          int ng = nb + r;
          int hv = (ng - 2048) >> 6, d = ng & 63;
          vT[((size_t)(b * 16 + hv) * HDIM + d) * SEQ + scol] =
              (bf16)acc[mi][ni][r];
        }
      }
    }
  } else {  // Q|K: fused RoPE on f32 acc, then bf16 store
#pragma unroll
    for (int mi = 0; mi < 4; ++mi) {
      int mb = m0 + wm * 64 + mi * 16 + quad * 4;
#pragma unroll
      for (int ni = 0; ni < 4; ++ni) {
        int n = n0 + wn * 64 + ni * 16 + l15;
        int pr = (n & 63) >> 1;
        float sgn = (n & 1) ? 1.f : -1.f;  // even: e*c - o*s ; odd: o*c + e*s
#pragma unroll
        for (int r = 0; r < 4; ++r) {
          float own = acc[mi][ni][r];
          float par = __shfl_xor(own, 1);
          int m = mb + r;
          float2 cs = tbl[m * 32 + pr];
          C[(size_t)m * N + n] = (bf16)(own * cs.x + sgn * par * cs.y);
        }
      }
    }
  }
}

// ---------------- GEMM 64x128 tile, f32 out (out-projection) ----------------
__global__ __launch_bounds__(256) void gemm_bt64(
    const bf16* __restrict__ A, const bf16* __restrict__ Bt,
    float* __restrict__ C, int M, int N, int K) {
  __shared__ __align__(16) bf16 a_lds[64 * 32];
  __shared__ __align__(16) bf16 b_lds[128 * 32];
  int tid = threadIdx.x;
  int wave = tid >> 6, lane = tid & 63;
  int quad = lane >> 4, l15 = lane & 15;
  int wm = wave >> 1, wn = wave & 1;

  int flat = blockIdx.y * gridDim.x + blockIdx.x;
  int mband = gridDim.y >> 3;  // m-tiles (64-row) per XCD band
  int xcd = flat & 7, sidx = flat >> 3;
  int m0 = (xcd * mband + (sidx % mband)) * 64;
  int n0 = (sidx / mband) * 128;

  f32x4 acc[2][4] = {};

  for (int kt = 0; kt < K; kt += 32) {
    __syncthreads();
    {  // A: 64 rows x 32 = 256 chunks, one per thread
      int row = tid >> 2, cc = (tid & 3) * 8;
      gload_lds16(A + (size_t)(m0 + row) * K + kt + cc,
                  (char*)a_lds + wave * 1024);
    }
#pragma unroll
    for (int call = 0; call < 2; ++call) {  // B: 128 rows x 32
      int chunk = call * 256 + tid;
      int row = chunk >> 2, cc = (chunk & 3) * 8;
      gload_lds16(Bt + (size_t)(n0 + row) * K + kt + cc,
                  (char*)b_lds + call * 4096 + wave * 1024);
    }
    __syncthreads();
    bf16x8 af[2], bfr[4];
#pragma unroll
    for (int i = 0; i < 2; ++i)
      af[i] = *(const bf16x8*)(a_lds + (wm * 32 + i * 16 + l15) * 32 + quad * 8);
#pragma unroll
    for (int i = 0; i < 4; ++i)
      bfr[i] = *(const bf16x8*)(b_lds + (wn * 64 + i * 16 + l15) * 32 + quad * 8);
#pragma unroll
    for (int mi = 0; mi < 2; ++mi)
#pragma unroll
      for (int ni = 0; ni < 4; ++ni)
        acc[mi][ni] = __builtin_amdgcn_mfma_f32_16x16x32_bf16(
            af[mi], bfr[ni], acc[mi][ni], 0, 0, 0);
  }

#pragma unroll
  for (int mi = 0; mi < 2; ++mi) {
    int mb = m0 + wm * 32 + mi * 16 + quad * 4;
#pragma unroll
    for (int ni = 0; ni < 4; ++ni) {
      int n = n0 + wn * 64 + ni * 16 + l15;
#pragma unroll
      for (int r = 0; r < 4; ++r)
        C[(size_t)(mb + r) * N + n] = acc[mi][ni][r];
    }
  }
}

// -------- causal flash attention, D=64, QBLK=64, 16x16 swapped+sigma --------
// R8-verified (42.7us): in-register P via swapped QK^T + sigma-permuted PV.
__global__ __launch_bounds__(256) void attn_fwd(
    const bf16* __restrict__ QKV, const bf16* __restrict__ VT,
    bf16* __restrict__ O) {
  __shared__ __align__(16) bf16 k_lds[2][64 * 72];  // [buf][kv][d]
  __shared__ __align__(16) bf16 v_lds[2][64 * 72];  // [buf][d][kv]
  const float C2 = 0.18033688011112042f;   // 0.125 * log2(e)
  const float C3 = -5.770780163555854f;    // -4 * log2(e)
  int tid = threadIdx.x;
  int wave = tid >> 6, lane = tid & 63;
  int quad = lane >> 4, l15 = lane & 15;
  int idx = blockIdx.x;
  int bh = idx & 31;                        // XCD pinning: idx%8 == bh%8
  int g = idx >> 5;                         // 0..31
  int qt = (g < 16) ? (31 - g) : (g - 16);  // bijection; heavy blocks first
  int q0 = qt * 64;
  int b = bh >> 4, h = bh & 15;
  const bf16* Qb = QKV + (size_t)b * SEQ * QKVW + h * 64;  // row stride QKVW
  const bf16* Kb = Qb + DM;
  const bf16* VTb = VT + (size_t)bh * HDIM * SEQ;          // [d][s]

  // Q B-frag (col=q=l15, k=d=8*quad+i within 32-slice)
  int qg = q0 + wave * 16 + l15;
  const bf16* qr = Qb + (size_t)qg * QKVW;
  bf16x8 qf0 = *(const bf16x8*)(qr + quad * 8);
  bf16x8 qf1 = *(const bf16x8*)(qr + 32 + quad * 8);

  int r0c = tid >> 3, off0 = (tid & 7) * 8;  // staging: row 0..31, off 0..56

  int niter = qt + 1;
  f32x4 oT[4] = {};     // PV acc: col d = dt*16+l15, row q = 4*quad+r
  float lsum = 0.f;     // partial denominator for q = l15 (this lane's slots)

  bf16x8 kpre0 = *(const bf16x8*)(Kb + (size_t)r0c * QKVW + off0);
  bf16x8 kpre1 = *(const bf16x8*)(Kb + (size_t)(r0c + 32) * QKVW + off0);
  bf16x8 vpre0 = *(const bf16x8*)(VTb + (size_t)r0c * SEQ + off0);
  bf16x8 vpre1 = *(const bf16x8*)(VTb + (size_t)(r0c + 32) * SEQ + off0);

  for (int tkv = 0; tkv < niter; ++tkv) {
    int kv0 = tkv * 64;
    bf16* kb = k_lds[tkv & 1];
    bf16* vb = v_lds[tkv & 1];
    *(bf16x8*)(kb + r0c * 72 + off0) = kpre0;
    *(bf16x8*)(kb + (r0c + 32) * 72 + off0) = kpre1;
    *(bf16x8*)(vb + r0c * 72 + off0) = vpre0;
    *(bf16x8*)(vb + (r0c + 32) * 72 + off0) = vpre1;
    __syncthreads();
    if (tkv + 1 < niter) {
      int kn = kv0 + 64;
      kpre0 = *(const bf16x8*)(Kb + (size_t)(kn + r0c) * QKVW + off0);
      kpre1 = *(const bf16x8*)(Kb + (size_t)(kn + r0c + 32) * QKVW + off0);
      vpre0 = *(const bf16x8*)(VTb + (size_t)r0c * SEQ + kn + off0);
      vpre1 = *(const bf16x8*)(VTb + (size_t)(r0c + 32) * SEQ + kn + off0);
    }
    // QK^T swapped: sT[nt] = K_nt x Q -> S^T[kv=nt*16+4*quad+r][q=l15]
    f32x4 sT[4];
    __builtin_amdgcn_s_setprio(1);
#pragma unroll
    for (int nt = 0; nt < 4; ++nt) {
      const bf16* kr = kb + (nt * 16 + l15) * 72;
      bf16x8 kf0 = *(const bf16x8*)(kr + quad * 8);
      bf16x8 kf1 = *(const bf16x8*)(kr + 32 + quad * 8);
      f32x4 z = {};
      z = __builtin_amdgcn_mfma_f32_16x16x32_bf16(kf0, qf0, z, 0, 0, 0);
      z = __builtin_amdgcn_mfma_f32_16x16x32_bf16(kf1, qf1, z, 0, 0, 0);
      sT[nt] = z;
    }
    __builtin_amdgcn_s_setprio(0);
    // softmax, lane-local: pv[nt][r] = P[kv0+nt*16+4*quad+r][qg]
    float pv[4][4];
    if (tkv == qt) {  // diagonal tile (wave-uniform branch)
#pragma unroll
      for (int nt = 0; nt < 4; ++nt)
#pragma unroll
        for (int r = 0; r < 4; ++r) {
          float p = __builtin_amdgcn_exp2f(sT[nt][r] * C2 + C3);
          int kvg = kv0 + nt * 16 + 4 * quad + r;
          if (kvg > qg) p = 0.f;
          pv[nt][r] = p;
          lsum += p;
        }
    } else {
#pragma unroll
      for (int nt = 0; nt < 4; ++nt)
#pragma unroll
        for (int r = 0; r < 4; ++r) {
          float p = __builtin_amdgcn_exp2f(sT[nt][r] * C2 + C3);
          pv[nt][r] = p;
          lsum += p;
        }
    }
    // pack P into sigma-ordered A-frags (lane-local):
    // pa0: k=8q+i -> kv = 4q + (i&3) + 16*(i>>2)        (kv 0..31)
    // pa1: same + 32                                     (kv 32..63)
    i32x4 w0 = {pk2(pv[0][0], pv[0][1]), pk2(pv[0][2], pv[0][3]),
                pk2(pv[1][0], pv[1][1]), pk2(pv[1][2], pv[1][3])};
    i32x4 w1 = {pk2(pv[2][0], pv[2][1]), pk2(pv[2][2], pv[2][3]),
                pk2(pv[3][0], pv[3][1]), pk2(pv[3][2], pv[3][3])};
    bf16x8 pa0 = __builtin_bit_cast(bf16x8, w0);
    bf16x8 pa1 = __builtin_bit_cast(bf16x8, w1);
    // PV: V B-frags read at sigma-matched offsets (two b64 per frag)
    __builtin_amdgcn_s_setprio(1);
#pragma unroll
    for (int dt = 0; dt < 4; ++dt) {
      const bf16* vd = vb + (dt * 16 + l15) * 72 + 4 * quad;
      bf16x4 a0 = *(const bf16x4*)(vd);        // kv 4q+0..3
      bf16x4 a1 = *(const bf16x4*)(vd + 16);   // kv 16+4q+0..3
      bf16x8 vf0 = __builtin_shufflevector(a0, a1, 0, 1, 2, 3, 4, 5, 6, 7);
      oT[dt] = __builtin_amdgcn_mfma_f32_16x16x32_bf16(pa0, vf0, oT[dt], 0, 0, 0);
      bf16x4 b0 = *(const bf16x4*)(vd + 32);   // kv 32+4q+0..3
      bf16x4 b1 = *(const bf16x4*)(vd + 48);   // kv 48+4q+0..3
      bf16x8 vf1 = __builtin_shufflevector(b0, b1, 0, 1, 2, 3, 4, 5, 6, 7);
      oT[dt] = __builtin_amdgcn_mfma_f32_16x16x32_bf16(pa1, vf1, oT[dt], 0, 0, 0);
    }
    __builtin_amdgcn_s_setprio(0);
  }
  // denominator: reduce lsum over quads (lanes sharing q=l15: xor16, xor32)
  float t = lsum;
  t += __shfl_xor(t, 16);
  t += __shfl_xor(t, 32);          // all lanes: t = L[q=l15]
  // epilogue: O row q = q0+wave*16+4*quad+r, col d = dt*16+l15
#pragma unroll
  for (int r = 0; r < 4; ++r) {
    float Lr = __shfl(t, 4 * quad + r);   // L for this row's q
    float inv = 1.f / Lr;
    int sq = q0 + wave * 16 + 4 * quad + r;
#pragma unroll
    for (int dt = 0; dt < 4; ++dt)
      O[(size_t)(b * SEQ + sq) * DM + h * HDIM + dt * 16 + l15] =
          (bf16)(oT[dt][r] * inv);
  }
}

extern "C" void kernel_launch(void* const* d_in, const int* in_sizes, int n_in,
                              void* d_out, int out_size, void* d_ws,
                              size_t ws_size, hipStream_t stream) {
  const float* hidden = (const float*)d_in[0];   // [2,2048,1024] f32
  const float* w_qkv  = (const float*)d_in[1];   // [1024,3072]  f32
  const float* w_out  = (const float*)d_in[2];   // [1024,1024]  f32
  const int*   pos    = (const int*)d_in[3];     // [2,2048,3]   i32
  float* out = (float*)d_out;                    // f32 output

  char* ws = (char*)d_ws;
  bf16* wqkvT  = (bf16*)ws;  ws += (size_t)3072 * 1024 * 2;
  bf16* woutT  = (bf16*)ws;  ws += (size_t)1024 * 1024 * 2;
  bf16* hid_bf = (bf16*)ws;  ws += (size_t)4096 * 1024 * 2;
  bf16* qkv_ws = (bf16*)ws;  ws += (size_t)4096 * 3072 * 2;
  bf16* vT_ws  = (bf16*)ws;  ws += (size_t)32 * SEQ * HDIM * 2;
  float2* ropetbl = (float2*)ws;  // 1 MB
  bf16* attn_ws = hid_bf;  // alias: hid_bf dead after gemm_qkv

  prep<<<dim3(3584), 256, 0, stream>>>(hidden, w_qkv, w_out, pos,
                                       hid_bf, wqkvT, woutT, ropetbl);
  gemm_qkv<<<dim3(24, 32), 256, 0, stream>>>(
      hid_bf, wqkvT, qkv_ws, ropetbl, vT_ws, 4096, 3072, 1024);
  attn_fwd<<<dim3(1024), 256, 0, stream>>>(qkv_ws, vT_ws, attn_ws);
  gemm_bt64<<<dim3(8, 64), 256, 0, stream>>>(
      attn_ws, woutT, out, 4096, 1024, 1024);
}

// Round 11
// 198.333 us; speedup vs baseline: 1.0826x; 1.0826x over previous
//
#include <hip/hip_runtime.h>
#include <hip/hip_bf16.h>
#include <math.h>

typedef __bf16 bf16;
typedef __bf16 bf16x4 __attribute__((ext_vector_type(4)));
typedef __bf16 bf16x8 __attribute__((ext_vector_type(8)));
typedef float f32x4 __attribute__((ext_vector_type(4)));
typedef int i32x4 __attribute__((ext_vector_type(4)));

#define SEQ 2048
#define NHEADS 16
#define HDIM 64
#define DM 1024
#define QKVW 3072

__device__ __forceinline__ void gload_lds16(const void* g, void* l) {
  __builtin_amdgcn_global_load_lds(
      (const __attribute__((address_space(1))) unsigned int*)g,
      (__attribute__((address_space(3))) unsigned int*)l, 16, 0, 0);
}

// pack two f32 -> one dword of 2 bf16 (lo = a, hi = b)
__device__ __forceinline__ int pk2(float a, float b) {
  union { __bf16 h; unsigned short u; } ua, ub;
  ua.h = (__bf16)a; ub.h = (__bf16)b;
  return (int)ua.u | ((int)ub.u << 16);
}

// ---------------- prep: cvt | transpose wqkv | transpose wout | rope table --
__global__ __launch_bounds__(256) void prep(
    const float* __restrict__ hidden, const float* __restrict__ w_qkv,
    const float* __restrict__ w_out, const int* __restrict__ pos,
    bf16* __restrict__ hid_bf, bf16* __restrict__ wqkvT,
    bf16* __restrict__ woutT, float2* __restrict__ tbl) {
  __shared__ float tile[64][65];
  int idx = blockIdx.x, tid = threadIdx.x;
  if (idx < 2048) {  // cvt f32->bf16, 8 elems/thread
    int i = (idx * 256 + tid) * 8;
    float4 a = *(const float4*)(hidden + i);
    float4 b = *(const float4*)(hidden + i + 4);
    bf16x8 o;
    o[0] = (bf16)a.x; o[1] = (bf16)a.y; o[2] = (bf16)a.z; o[3] = (bf16)a.w;
    o[4] = (bf16)b.x; o[5] = (bf16)b.y; o[6] = (bf16)b.z; o[7] = (bf16)b.w;
    *(bf16x8*)(hid_bf + i) = o;
  } else if (idx < 3072) {  // weight transposes f32 -> bf16^T
    const float* in; bf16* out; int R, C, t;
    if (idx < 2816) { t = idx - 2048; in = w_qkv; out = wqkvT; R = 1024; C = 3072; }
    else            { t = idx - 2816; in = w_out; out = woutT; R = 1024; C = 1024; }
    int nbx = C >> 6;
    int c0 = (t % nbx) * 64, r0 = (t / nbx) * 64;
    int col = tid & 63, rb = (tid >> 6) * 16;
#pragma unroll
    for (int i = 0; i < 16; ++i)
      tile[rb + i][col] = in[(size_t)(r0 + rb + i) * C + c0 + col];
    __syncthreads();
#pragma unroll
    for (int i = 0; i < 16; ++i)
      out[(size_t)(c0 + rb + i) * R + r0 + col] = (bf16)tile[col][rb + i];
  } else {  // rope table: tbl[m][pair] = (cos, sin)
    const float LN1E4 = 9.210340371976184f;
    int gi = (idx - 3072) * 256 + tid;  // 4096*32
    int m = gi >> 5, pr = gi & 31;
    int axis, d, iloc;
    if (pr < 10)      { axis = 0; d = 20; iloc = pr; }
    else if (pr < 20) { axis = 1; d = 20; iloc = pr - 10; }
    else              { axis = 2; d = 24; iloc = pr - 20; }
    int p = pos[m * 3 + axis];
    int pmax = (axis == 2) ? 7 : 31;
    p = p < 0 ? 0 : (p > pmax ? pmax : p);
    float invf = __expf(-((float)(2 * iloc) / (float)d) * LN1E4);
    float sn, cs;
    __sincosf((float)p * invf, &sn, &cs);
    tbl[gi] = make_float2(cs, sn);
  }
}

// ---------------- post_qkv: in-place RoPE on Q|K  |  V^T build --------------
__global__ __launch_bounds__(256) void post_qkv(
    bf16* __restrict__ qkv, const float2* __restrict__ tbl,
    bf16* __restrict__ vT) {
  __shared__ bf16 btile[64][65];
  int idx = blockIdx.x, tid = threadIdx.x;
  if (idx < 2048) {  // rope: thread = 16 contiguous elems (8 pairs)
    int gi = idx * 256 + tid;
    int m = gi >> 7, seg = gi & 127;
    bf16* p = qkv + (size_t)m * QKVW + seg * 16;
    bf16x8 a = *(const bf16x8*)p;
    bf16x8 b2 = *(const bf16x8*)(p + 8);
    const float2* t = tbl + m * 32 + (((seg * 16) & 63) >> 1);
#pragma unroll
    for (int j = 0; j < 4; ++j) {
      float2 cs = t[j];
      float e = (float)a[2 * j], o = (float)a[2 * j + 1];
      a[2 * j]     = (bf16)(e * cs.x - o * cs.y);
      a[2 * j + 1] = (bf16)(o * cs.x + e * cs.y);
    }
#pragma unroll
    for (int j = 0; j < 4; ++j) {
      float2 cs = t[4 + j];
      float e = (float)b2[2 * j], o = (float)b2[2 * j + 1];
      b2[2 * j]     = (bf16)(e * cs.x - o * cs.y);
      b2[2 * j + 1] = (bf16)(o * cs.x + e * cs.y);
    }
    *(bf16x8*)p = a;
    *(bf16x8*)(p + 8) = b2;
  } else {  // vT build: [s][d] -> [bh][d][s]
    int t = idx - 2048;
    int s0 = (t & 31) * 64, bh = t >> 5;
    int b = bh >> 4, h = bh & 15;
    const bf16* src = qkv + (size_t)(b * SEQ + s0) * QKVW + 2 * DM + h * 64;
    int col = tid & 63, rb = (tid >> 6) * 16;
#pragma unroll
    for (int i = 0; i < 16; ++i)
      btile[rb + i][col] = src[(size_t)(rb + i) * QKVW + col];
    __syncthreads();
    bf16* dst = vT + (size_t)bh * HDIM * SEQ + s0;
#pragma unroll
    for (int i = 0; i < 16; ++i)
      dst[(size_t)(rb + i) * SEQ + col] = btile[col][rb + i];
  }
}

// ---------------- GEMM 128x128: C(bf16) = A[M,K] * Bt[N,K]^T ----------------
__global__ __launch_bounds__(256) void gemm_bt(
    const bf16* __restrict__ A, const bf16* __restrict__ Bt,
    bf16* __restrict__ C, int M, int N, int K) {
  __shared__ __align__(16) bf16 a_lds[128 * 32];
  __shared__ __align__(16) bf16 b_lds[128 * 32];
  int tid = threadIdx.x;
  int wave = tid >> 6, lane = tid & 63;
  int quad = lane >> 4, l15 = lane & 15;
  int wm = wave >> 1, wn = wave & 1;

  int flat = blockIdx.y * gridDim.x + blockIdx.x;
  int mband = gridDim.y >> 3;
  int xcd = flat & 7, sidx = flat >> 3;
  int m0 = (xcd * mband + (sidx % mband)) * 128;
  int n0 = (sidx / mband) * 128;

  f32x4 acc[4][4] = {};

  for (int kt = 0; kt < K; kt += 32) {
    __syncthreads();
#pragma unroll
    for (int call = 0; call < 2; ++call) {
      int chunk = call * 256 + tid;
      int row = chunk >> 2, cc = (chunk & 3) * 8;
      gload_lds16(A + (size_t)(m0 + row) * K + kt + cc,
                  (char*)a_lds + call * 4096 + wave * 1024);
      gload_lds16(Bt + (size_t)(n0 + row) * K + kt + cc,
                  (char*)b_lds + call * 4096 + wave * 1024);
    }
    __syncthreads();
    bf16x8 af[4], bfr[4];
#pragma unroll
    for (int i = 0; i < 4; ++i) {
      af[i]  = *(const bf16x8*)(a_lds + (wm * 64 + i * 16 + l15) * 32 + quad * 8);
      bfr[i] = *(const bf16x8*)(b_lds + (wn * 64 + i * 16 + l15) * 32 + quad * 8);
    }
#pragma unroll
    for (int mi = 0; mi < 4; ++mi)
#pragma unroll
      for (int ni = 0; ni < 4; ++ni)
        acc[mi][ni] = __builtin_amdgcn_mfma_f32_16x16x32_bf16(
            af[mi], bfr[ni], acc[mi][ni], 0, 0, 0);
  }

#pragma unroll
  for (int mi = 0; mi < 4; ++mi) {
    int mb = m0 + wm * 64 + mi * 16 + quad * 4;
#pragma unroll
    for (int ni = 0; ni < 4; ++ni) {
      int n = n0 + wn * 64 + ni * 16 + l15;
#pragma unroll
      for (int r = 0; r < 4; ++r)
        C[(size_t)(mb + r) * N + n] = (bf16)acc[mi][ni][r];
    }
  }
}

// ---------------- GEMM 64x128 tile, f32 out (out-projection) ----------------
__global__ __launch_bounds__(256) void gemm_bt64(
    const bf16* __restrict__ A, const bf16* __restrict__ Bt,
    float* __restrict__ C, int M, int N, int K) {
  __shared__ __align__(16) bf16 a_lds[64 * 32];
  __shared__ __align__(16) bf16 b_lds[128 * 32];
  int tid = threadIdx.x;
  int wave = tid >> 6, lane = tid & 63;
  int quad = lane >> 4, l15 = lane & 15;
  int wm = wave >> 1, wn = wave & 1;

  int flat = blockIdx.y * gridDim.x + blockIdx.x;
  int mband = gridDim.y >> 3;  // m-tiles (64-row) per XCD band
  int xcd = flat & 7, sidx = flat >> 3;
  int m0 = (xcd * mband + (sidx % mband)) * 64;
  int n0 = (sidx / mband) * 128;

  f32x4 acc[2][4] = {};

  for (int kt = 0; kt < K; kt += 32) {
    __syncthreads();
    {  // A: 64 rows x 32 = 256 chunks, one per thread
      int row = tid >> 2, cc = (tid & 3) * 8;
      gload_lds16(A + (size_t)(m0 + row) * K + kt + cc,
                  (char*)a_lds + wave * 1024);
    }
#pragma unroll
    for (int call = 0; call < 2; ++call) {  // B: 128 rows x 32
      int chunk = call * 256 + tid;
      int row = chunk >> 2, cc = (chunk & 3) * 8;
      gload_lds16(Bt + (size_t)(n0 + row) * K + kt + cc,
                  (char*)b_lds + call * 4096 + wave * 1024);
    }
    __syncthreads();
    bf16x8 af[2], bfr[4];
#pragma unroll
    for (int i = 0; i < 2; ++i)
      af[i] = *(const bf16x8*)(a_lds + (wm * 32 + i * 16 + l15) * 32 + quad * 8);
#pragma unroll
    for (int i = 0; i < 4; ++i)
      bfr[i] = *(const bf16x8*)(b_lds + (wn * 64 + i * 16 + l15) * 32 + quad * 8);
#pragma unroll
    for (int mi = 0; mi < 2; ++mi)
#pragma unroll
      for (int ni = 0; ni < 4; ++ni)
        acc[mi][ni] = __builtin_amdgcn_mfma_f32_16x16x32_bf16(
            af[mi], bfr[ni], acc[mi][ni], 0, 0, 0);
  }

#pragma unroll
  for (int mi = 0; mi < 2; ++mi) {
    int mb = m0 + wm * 32 + mi * 16 + quad * 4;
#pragma unroll
    for (int ni = 0; ni < 4; ++ni) {
      int n = n0 + wn * 64 + ni * 16 + l15;
#pragma unroll
      for (int r = 0; r < 4; ++r)
        C[(size_t)(mb + r) * N + n] = acc[mi][ni][r];
    }
  }
}

// -------- causal flash attention: R8 base + 2-deep pipeline (T15) -----------
// Iter t: QK(t) on MFMA pipe; softmax+pack+PV of tile t-1 overlapped (VALU /
// MFMA). V-fragments are ds_read into REGISTERS in their own iteration (safe
// window, same single-barrier proof as R8); only the PV MFMAs are deferred.
// Interior finishes never need the causal mask (only tile qt is diagonal,
// finished post-loop).
__global__ __launch_bounds__(256, 4) void attn_fwd(
    const bf16* __restrict__ QKV, const bf16* __restrict__ VT,
    bf16* __restrict__ O) {
  __shared__ __align__(16) bf16 k_lds[2][64 * 72];  // [buf][kv][d]
  __shared__ __align__(16) bf16 v_lds[2][64 * 72];  // [buf][d][kv]
  const float C2 = 0.18033688011112042f;   // 0.125 * log2(e)
  const float C3 = -5.770780163555854f;    // -4 * log2(e)
  int tid = threadIdx.x;
  int wave = tid >> 6, lane = tid & 63;
  int quad = lane >> 4, l15 = lane & 15;
  int idx = blockIdx.x;
  int bh = idx & 31;                        // XCD pinning: idx%8 == bh%8
  int g = idx >> 5;                         // 0..31
  int qt = (g < 16) ? (31 - g) : (g - 16);  // bijection; per-CU load uniform
  int q0 = qt * 64;
  int b = bh >> 4, h = bh & 15;
  const bf16* Qb = QKV + (size_t)b * SEQ * QKVW + h * 64;  // row stride QKVW
  const bf16* Kb = Qb + DM;
  const bf16* VTb = VT + (size_t)bh * HDIM * SEQ;          // [d][s]

  // Q B-frag (col=q=l15, k=d=8*quad+i within 32-slice)
  int qg = q0 + wave * 16 + l15;
  const bf16* qr = Qb + (size_t)qg * QKVW;
  bf16x8 qf0 = *(const bf16x8*)(qr + quad * 8);
  bf16x8 qf1 = *(const bf16x8*)(qr + 32 + quad * 8);

  int r0c = tid >> 3, off0 = (tid & 7) * 8;  // staging: row 0..31, off 0..56

  int niter = qt + 1;
  f32x4 oT[4] = {};     // PV acc: col d = dt*16+l15, row q = 4*quad+r
  float lsum = 0.f;

  f32x4 sPrev[4];       // deferred S^T of previous tile
  bf16x8 vpf0[4], vpf1[4];  // sigma-ordered V frags of previous tile (regs)

  bf16x8 kpre0 = *(const bf16x8*)(Kb + (size_t)r0c * QKVW + off0);
  bf16x8 kpre1 = *(const bf16x8*)(Kb + (size_t)(r0c + 32) * QKVW + off0);
  bf16x8 vpre0 = *(const bf16x8*)(VTb + (size_t)r0c * SEQ + off0);
  bf16x8 vpre1 = *(const bf16x8*)(VTb + (size_t)(r0c + 32) * SEQ + off0);

  for (int tkv = 0; tkv < niter; ++tkv) {
    bf16* kb = k_lds[tkv & 1];
    bf16* vb = v_lds[tkv & 1];
    *(bf16x8*)(kb + r0c * 72 + off0) = kpre0;
    *(bf16x8*)(kb + (r0c + 32) * 72 + off0) = kpre1;
    *(bf16x8*)(vb + r0c * 72 + off0) = vpre0;
    *(bf16x8*)(vb + (r0c + 32) * 72 + off0) = vpre1;
    __syncthreads();
    if (tkv + 1 < niter) {
      int kn = tkv * 64 + 64;
      kpre0 = *(const bf16x8*)(Kb + (size_t)(kn + r0c) * QKVW + off0);
      kpre1 = *(const bf16x8*)(Kb + (size_t)(kn + r0c + 32) * QKVW + off0);
      vpre0 = *(const bf16x8*)(VTb + (size_t)r0c * SEQ + kn + off0);
      vpre1 = *(const bf16x8*)(VTb + (size_t)(r0c + 32) * SEQ + kn + off0);
    }
    // QK^T(t) swapped: sCur[nt] = S^T[kv=nt*16+4*quad+r][q=l15]
    f32x4 sCur[4];
    __builtin_amdgcn_s_setprio(1);
#pragma unroll
    for (int nt = 0; nt < 4; ++nt) {
      const bf16* kr = kb + (nt * 16 + l15) * 72;
      bf16x8 kf0 = *(const bf16x8*)(kr + quad * 8);
      bf16x8 kf1 = *(const bf16x8*)(kr + 32 + quad * 8);
      f32x4 z = {};
      z = __builtin_amdgcn_mfma_f32_16x16x32_bf16(kf0, qf0, z, 0, 0, 0);
      z = __builtin_amdgcn_mfma_f32_16x16x32_bf16(kf1, qf1, z, 0, 0, 0);
      sCur[nt] = z;
    }
    __builtin_amdgcn_s_setprio(0);
    if (tkv > 0) {  // finish tile t-1 (interior: no mask)
      float pv[4][4];
#pragma unroll
      for (int nt = 0; nt < 4; ++nt)
#pragma unroll
        for (int r = 0; r < 4; ++r) {
          float p = __builtin_amdgcn_exp2f(sPrev[nt][r] * C2 + C3);
          pv[nt][r] = p;
          lsum += p;
        }
      i32x4 w0 = {pk2(pv[0][0], pv[0][1]), pk2(pv[0][2], pv[0][3]),
                  pk2(pv[1][0], pv[1][1]), pk2(pv[1][2], pv[1][3])};
      i32x4 w1 = {pk2(pv[2][0], pv[2][1]), pk2(pv[2][2], pv[2][3]),
                  pk2(pv[3][0], pv[3][1]), pk2(pv[3][2], pv[3][3])};
      bf16x8 pa0 = __builtin_bit_cast(bf16x8, w0);
      bf16x8 pa1 = __builtin_bit_cast(bf16x8, w1);
      __builtin_amdgcn_s_setprio(1);
#pragma unroll
      for (int dt = 0; dt < 4; ++dt) {
        oT[dt] = __builtin_amdgcn_mfma_f32_16x16x32_bf16(pa0, vpf0[dt], oT[dt], 0, 0, 0);
        oT[dt] = __builtin_amdgcn_mfma_f32_16x16x32_bf16(pa1, vpf1[dt], oT[dt], 0, 0, 0);
      }
      __builtin_amdgcn_s_setprio(0);
    }
    // load V(t) sigma-frags into registers (own-iteration read: race-free)
#pragma unroll
    for (int dt = 0; dt < 4; ++dt) {
      const bf16* vd = vb + (dt * 16 + l15) * 72 + 4 * quad;
      bf16x4 a0 = *(const bf16x4*)(vd);        // kv 4q+0..3
      bf16x4 a1 = *(const bf16x4*)(vd + 16);   // kv 16+4q+0..3
      vpf0[dt] = __builtin_shufflevector(a0, a1, 0, 1, 2, 3, 4, 5, 6, 7);
      bf16x4 b0 = *(const bf16x4*)(vd + 32);   // kv 32+4q+0..3
      bf16x4 b1 = *(const bf16x4*)(vd + 48);   // kv 48+4q+0..3
      vpf1[dt] = __builtin_shufflevector(b0, b1, 0, 1, 2, 3, 4, 5, 6, 7);
    }
    sPrev[0] = sCur[0]; sPrev[1] = sCur[1];
    sPrev[2] = sCur[2]; sPrev[3] = sCur[3];
  }
  {  // final tile (tkv = qt): diagonal, masked finish
    int kv0 = (niter - 1) * 64;
    float pv[4][4];
#pragma unroll
    for (int nt = 0; nt < 4; ++nt)
#pragma unroll
      for (int r = 0; r < 4; ++r) {
        float p = __builtin_amdgcn_exp2f(sPrev[nt][r] * C2 + C3);
        int kvg = kv0 + nt * 16 + 4 * quad + r;
        if (kvg > qg) p = 0.f;
        pv[nt][r] = p;
        lsum += p;
      }
    i32x4 w0 = {pk2(pv[0][0], pv[0][1]), pk2(pv[0][2], pv[0][3]),
                pk2(pv[1][0], pv[1][1]), pk2(pv[1][2], pv[1][3])};
    i32x4 w1 = {pk2(pv[2][0], pv[2][1]), pk2(pv[2][2], pv[2][3]),
                pk2(pv[3][0], pv[3][1]), pk2(pv[3][2], pv[3][3])};
    bf16x8 pa0 = __builtin_bit_cast(bf16x8, w0);
    bf16x8 pa1 = __builtin_bit_cast(bf16x8, w1);
#pragma unroll
    for (int dt = 0; dt < 4; ++dt) {
      oT[dt] = __builtin_amdgcn_mfma_f32_16x16x32_bf16(pa0, vpf0[dt], oT[dt], 0, 0, 0);
      oT[dt] = __builtin_amdgcn_mfma_f32_16x16x32_bf16(pa1, vpf1[dt], oT[dt], 0, 0, 0);
    }
  }
  // denominator: reduce lsum over quads (lanes sharing q=l15: xor16, xor32)
  float t = lsum;
  t += __shfl_xor(t, 16);
  t += __shfl_xor(t, 32);          // all lanes: t = L[q=l15]
  // epilogue: O row q = q0+wave*16+4*quad+r, col d = dt*16+l15
#pragma unroll
  for (int r = 0; r < 4; ++r) {
    float Lr = __shfl(t, 4 * quad + r);   // L for this row's q
    float inv = 1.f / Lr;
    int sq = q0 + wave * 16 + 4 * quad + r;
#pragma unroll
    for (int dt = 0; dt < 4; ++dt)
      O[(size_t)(b * SEQ + sq) * DM + h * HDIM + dt * 16 + l15] =
          (bf16)(oT[dt][r] * inv);
  }
}

extern "C" void kernel_launch(void* const* d_in, const int* in_sizes, int n_in,
                              void* d_out, int out_size, void* d_ws,
                              size_t ws_size, hipStream_t stream) {
  const float* hidden = (const float*)d_in[0];   // [2,2048,1024] f32
  const float* w_qkv  = (const float*)d_in[1];   // [1024,3072]  f32
  const float* w_out  = (const float*)d_in[2];   // [1024,1024]  f32
  const int*   pos    = (const int*)d_in[3];     // [2,2048,3]   i32
  float* out = (float*)d_out;                    // f32 output

  char* ws = (char*)d_ws;
  bf16* wqkvT  = (bf16*)ws;  ws += (size_t)3072 * 1024 * 2;
  bf16* woutT  = (bf16*)ws;  ws += (size_t)1024 * 1024 * 2;
  bf16* hid_bf = (bf16*)ws;  ws += (size_t)4096 * 1024 * 2;
  bf16* qkv_ws = (bf16*)ws;  ws += (size_t)4096 * 3072 * 2;
  bf16* vT_ws  = (bf16*)ws;  ws += (size_t)32 * SEQ * HDIM * 2;
  float2* ropetbl = (float2*)ws;  // 1 MB
  bf16* attn_ws = hid_bf;  // alias: hid_bf dead after gemm_bt

  prep<<<dim3(3584), 256, 0, stream>>>(hidden, w_qkv, w_out, pos,
                                       hid_bf, wqkvT, woutT, ropetbl);
  gemm_bt<<<dim3(24, 32), 256, 0, stream>>>(
      hid_bf, wqkvT, qkv_ws, 4096, 3072, 1024);
  post_qkv<<<dim3(3072), 256, 0, stream>>>(qkv_ws, ropetbl, vT_ws);
  attn_fwd<<<dim3(1024), 256, 0, stream>>>(qkv_ws, vT_ws, attn_ws);
  gemm_bt64<<<dim3(8, 64), 256, 0, stream>>>(
      attn_ws, woutT, out, 4096, 1024, 1024);
}

// Round 12
// 194.770 us; speedup vs baseline: 1.1024x; 1.0183x over previous
//
#include <hip/hip_runtime.h>
#include <hip/hip_bf16.h>
#include <math.h>

typedef __bf16 bf16;
typedef __bf16 bf16x4 __attribute__((ext_vector_type(4)));
typedef __bf16 bf16x8 __attribute__((ext_vector_type(8)));
typedef float f32x4 __attribute__((ext_vector_type(4)));
typedef int i32x4 __attribute__((ext_vector_type(4)));

#define SEQ 2048
#define NHEADS 16
#define HDIM 64
#define DM 1024
#define QKVW 3072

__device__ __forceinline__ void gload_lds16(const void* g, void* l) {
  __builtin_amdgcn_global_load_lds(
      (const __attribute__((address_space(1))) unsigned int*)g,
      (__attribute__((address_space(3))) unsigned int*)l, 16, 0, 0);
}

// pack two f32 -> one dword of 2 bf16 (lo = a, hi = b)
__device__ __forceinline__ int pk2(float a, float b) {
  union { __bf16 h; unsigned short u; } ua, ub;
  ua.h = (__bf16)a; ub.h = (__bf16)b;
  return (int)ua.u | ((int)ub.u << 16);
}

// ---------------- prep: cvt | transpose wqkv | transpose wout | rope table --
__global__ __launch_bounds__(256) void prep(
    const float* __restrict__ hidden, const float* __restrict__ w_qkv,
    const float* __restrict__ w_out, const int* __restrict__ pos,
    bf16* __restrict__ hid_bf, bf16* __restrict__ wqkvT,
    bf16* __restrict__ woutT, float2* __restrict__ tbl) {
  __shared__ float tile[64][65];
  int idx = blockIdx.x, tid = threadIdx.x;
  if (idx < 2048) {  // cvt f32->bf16, 8 elems/thread
    int i = (idx * 256 + tid) * 8;
    float4 a = *(const float4*)(hidden + i);
    float4 b = *(const float4*)(hidden + i + 4);
    bf16x8 o;
    o[0] = (bf16)a.x; o[1] = (bf16)a.y; o[2] = (bf16)a.z; o[3] = (bf16)a.w;
    o[4] = (bf16)b.x; o[5] = (bf16)b.y; o[6] = (bf16)b.z; o[7] = (bf16)b.w;
    *(bf16x8*)(hid_bf + i) = o;
  } else if (idx < 3072) {  // weight transposes f32 -> bf16^T
    const float* in; bf16* out; int R, C, t;
    if (idx < 2816) { t = idx - 2048; in = w_qkv; out = wqkvT; R = 1024; C = 3072; }
    else            { t = idx - 2816; in = w_out; out = woutT; R = 1024; C = 1024; }
    int nbx = C >> 6;
    int c0 = (t % nbx) * 64, r0 = (t / nbx) * 64;
    int col = tid & 63, rb = (tid >> 6) * 16;
#pragma unroll
    for (int i = 0; i < 16; ++i)
      tile[rb + i][col] = in[(size_t)(r0 + rb + i) * C + c0 + col];
    __syncthreads();
#pragma unroll
    for (int i = 0; i < 16; ++i)
      out[(size_t)(c0 + rb + i) * R + r0 + col] = (bf16)tile[col][rb + i];
  } else {  // rope table: tbl[m][pair] = (cos, sin)
    const float LN1E4 = 9.210340371976184f;
    int gi = (idx - 3072) * 256 + tid;  // 4096*32
    int m = gi >> 5, pr = gi & 31;
    int axis, d, iloc;
    if (pr < 10)      { axis = 0; d = 20; iloc = pr; }
    else if (pr < 20) { axis = 1; d = 20; iloc = pr - 10; }
    else              { axis = 2; d = 24; iloc = pr - 20; }
    int p = pos[m * 3 + axis];
    int pmax = (axis == 2) ? 7 : 31;
    p = p < 0 ? 0 : (p > pmax ? pmax : p);
    float invf = __expf(-((float)(2 * iloc) / (float)d) * LN1E4);
    float sn, cs;
    __sincosf((float)p * invf, &sn, &cs);
    tbl[gi] = make_float2(cs, sn);
  }
}

// ---------------- post_qkv: in-place RoPE on Q|K  |  V^T build --------------
__global__ __launch_bounds__(256) void post_qkv(
    bf16* __restrict__ qkv, const float2* __restrict__ tbl,
    bf16* __restrict__ vT) {
  __shared__ bf16 btile[64][65];
  int idx = blockIdx.x, tid = threadIdx.x;
  if (idx < 2048) {  // rope: thread = 16 contiguous elems (8 pairs)
    int gi = idx * 256 + tid;
    int m = gi >> 7, seg = gi & 127;
    bf16* p = qkv + (size_t)m * QKVW + seg * 16;
    bf16x8 a = *(const bf16x8*)p;
    bf16x8 b2 = *(const bf16x8*)(p + 8);
    const float2* t = tbl + m * 32 + (((seg * 16) & 63) >> 1);
#pragma unroll
    for (int j = 0; j < 4; ++j) {
      float2 cs = t[j];
      float e = (float)a[2 * j], o = (float)a[2 * j + 1];
      a[2 * j]     = (bf16)(e * cs.x - o * cs.y);
      a[2 * j + 1] = (bf16)(o * cs.x + e * cs.y);
    }
#pragma unroll
    for (int j = 0; j < 4; ++j) {
      float2 cs = t[4 + j];
      float e = (float)b2[2 * j], o = (float)b2[2 * j + 1];
      b2[2 * j]     = (bf16)(e * cs.x - o * cs.y);
      b2[2 * j + 1] = (bf16)(o * cs.x + e * cs.y);
    }
    *(bf16x8*)p = a;
    *(bf16x8*)(p + 8) = b2;
  } else {  // vT build: [s][d] -> [bh][d][s]
    int t = idx - 2048;
    int s0 = (t & 31) * 64, bh = t >> 5;
    int b = bh >> 4, h = bh & 15;
    const bf16* src = qkv + (size_t)(b * SEQ + s0) * QKVW + 2 * DM + h * 64;
    int col = tid & 63, rb = (tid >> 6) * 16;
#pragma unroll
    for (int i = 0; i < 16; ++i)
      btile[rb + i][col] = src[(size_t)(rb + i) * QKVW + col];
    __syncthreads();
    bf16* dst = vT + (size_t)bh * HDIM * SEQ + s0;
#pragma unroll
    for (int i = 0; i < 16; ++i)
      dst[(size_t)(rb + i) * SEQ + col] = btile[col][rb + i];
  }
}

// ------- GEMM 128x128, BK=64: C(bf16) = A[M,K] * Bt[N,K]^T ------------------
// BK 32->64: 16 K-steps instead of 32 -> half the barrier+vmcnt(0) drains,
// 32 MFMA/wave between drains. LDS kept as TWO independent [128][32]
// sub-buffers per operand (staging + frag reads byte-identical to the
// verified BK=32 pattern, instantiated per k-slice) -> bank behavior and
// gload_lds destination linearity unchanged. LDS 32KB (cap 5/CU > grid 3/CU).
__global__ __launch_bounds__(256) void gemm_bt(
    const bf16* __restrict__ A, const bf16* __restrict__ Bt,
    bf16* __restrict__ C, int M, int N, int K) {
  __shared__ __align__(16) bf16 a_lds[2][128 * 32];
  __shared__ __align__(16) bf16 b_lds[2][128 * 32];
  int tid = threadIdx.x;
  int wave = tid >> 6, lane = tid & 63;
  int quad = lane >> 4, l15 = lane & 15;
  int wm = wave >> 1, wn = wave & 1;

  int flat = blockIdx.y * gridDim.x + blockIdx.x;
  int mband = gridDim.y >> 3;
  int xcd = flat & 7, sidx = flat >> 3;
  int m0 = (xcd * mband + (sidx % mband)) * 128;
  int n0 = (sidx / mband) * 128;

  f32x4 acc[4][4] = {};

  for (int kt = 0; kt < K; kt += 64) {
    __syncthreads();
#pragma unroll
    for (int ks = 0; ks < 2; ++ks)
#pragma unroll
      for (int call = 0; call < 2; ++call) {
        int chunk = call * 256 + tid;
        int row = chunk >> 2, cc = (chunk & 3) * 8;
        gload_lds16(A + (size_t)(m0 + row) * K + kt + ks * 32 + cc,
                    (char*)a_lds[ks] + call * 4096 + wave * 1024);
        gload_lds16(Bt + (size_t)(n0 + row) * K + kt + ks * 32 + cc,
                    (char*)b_lds[ks] + call * 4096 + wave * 1024);
      }
    __syncthreads();
    bf16x8 af[2][4], bfr[2][4];
#pragma unroll
    for (int ks = 0; ks < 2; ++ks)
#pragma unroll
      for (int i = 0; i < 4; ++i) {
        af[ks][i]  = *(const bf16x8*)(a_lds[ks] + (wm * 64 + i * 16 + l15) * 32 + quad * 8);
        bfr[ks][i] = *(const bf16x8*)(b_lds[ks] + (wn * 64 + i * 16 + l15) * 32 + quad * 8);
      }
#pragma unroll
    for (int mi = 0; mi < 4; ++mi)
#pragma unroll
      for (int ni = 0; ni < 4; ++ni) {
        acc[mi][ni] = __builtin_amdgcn_mfma_f32_16x16x32_bf16(
            af[0][mi], bfr[0][ni], acc[mi][ni], 0, 0, 0);
        acc[mi][ni] = __builtin_amdgcn_mfma_f32_16x16x32_bf16(
            af[1][mi], bfr[1][ni], acc[mi][ni], 0, 0, 0);
      }
  }

#pragma unroll
  for (int mi = 0; mi < 4; ++mi) {
    int mb = m0 + wm * 64 + mi * 16 + quad * 4;
#pragma unroll
    for (int ni = 0; ni < 4; ++ni) {
      int n = n0 + wn * 64 + ni * 16 + l15;
#pragma unroll
      for (int r = 0; r < 4; ++r)
        C[(size_t)(mb + r) * N + n] = (bf16)acc[mi][ni][r];
    }
  }
}

// ---------------- GEMM 64x128 tile, f32 out (out-projection) ----------------
__global__ __launch_bounds__(256) void gemm_bt64(
    const bf16* __restrict__ A, const bf16* __restrict__ Bt,
    float* __restrict__ C, int M, int N, int K) {
  __shared__ __align__(16) bf16 a_lds[64 * 32];
  __shared__ __align__(16) bf16 b_lds[128 * 32];
  int tid = threadIdx.x;
  int wave = tid >> 6, lane = tid & 63;
  int quad = lane >> 4, l15 = lane & 15;
  int wm = wave >> 1, wn = wave & 1;

  int flat = blockIdx.y * gridDim.x + blockIdx.x;
  int mband = gridDim.y >> 3;  // m-tiles (64-row) per XCD band
  int xcd = flat & 7, sidx = flat >> 3;
  int m0 = (xcd * mband + (sidx % mband)) * 64;
  int n0 = (sidx / mband) * 128;

  f32x4 acc[2][4] = {};

  for (int kt = 0; kt < K; kt += 32) {
    __syncthreads();
    {  // A: 64 rows x 32 = 256 chunks, one per thread
      int row = tid >> 2, cc = (tid & 3) * 8;
      gload_lds16(A + (size_t)(m0 + row) * K + kt + cc,
                  (char*)a_lds + wave * 1024);
    }
#pragma unroll
    for (int call = 0; call < 2; ++call) {  // B: 128 rows x 32
      int chunk = call * 256 + tid;
      int row = chunk >> 2, cc = (chunk & 3) * 8;
      gload_lds16(Bt + (size_t)(n0 + row) * K + kt + cc,
                  (char*)b_lds + call * 4096 + wave * 1024);
    }
    __syncthreads();
    bf16x8 af[2], bfr[4];
#pragma unroll
    for (int i = 0; i < 2; ++i)
      af[i] = *(const bf16x8*)(a_lds + (wm * 32 + i * 16 + l15) * 32 + quad * 8);
#pragma unroll
    for (int i = 0; i < 4; ++i)
      bfr[i] = *(const bf16x8*)(b_lds + (wn * 64 + i * 16 + l15) * 32 + quad * 8);
#pragma unroll
    for (int mi = 0; mi < 2; ++mi)
#pragma unroll
      for (int ni = 0; ni < 4; ++ni)
        acc[mi][ni] = __builtin_amdgcn_mfma_f32_16x16x32_bf16(
            af[mi], bfr[ni], acc[mi][ni], 0, 0, 0);
  }

#pragma unroll
  for (int mi = 0; mi < 2; ++mi) {
    int mb = m0 + wm * 32 + mi * 16 + quad * 4;
#pragma unroll
    for (int ni = 0; ni < 4; ++ni) {
      int n = n0 + wn * 64 + ni * 16 + l15;
#pragma unroll
      for (int r = 0; r < 4; ++r)
        C[(size_t)(mb + r) * N + n] = acc[mi][ni][r];
    }
  }
}

// -------- causal flash attention: R8 base + 2-deep pipeline (T15) -----------
// Iter t: QK(t) on MFMA pipe; softmax+pack+PV of tile t-1 overlapped (VALU /
// MFMA). V-fragments are ds_read into REGISTERS in their own iteration (safe
// window, same single-barrier proof as R8); only the PV MFMAs are deferred.
// Interior finishes never need the causal mask (only tile qt is diagonal,
// finished post-loop).
__global__ __launch_bounds__(256, 4) void attn_fwd(
    const bf16* __restrict__ QKV, const bf16* __restrict__ VT,
    bf16* __restrict__ O) {
  __shared__ __align__(16) bf16 k_lds[2][64 * 72];  // [buf][kv][d]
  __shared__ __align__(16) bf16 v_lds[2][64 * 72];  // [buf][d][kv]
  const float C2 = 0.18033688011112042f;   // 0.125 * log2(e)
  const float C3 = -5.770780163555854f;    // -4 * log2(e)
  int tid = threadIdx.x;
  int wave = tid >> 6, lane = tid & 63;
  int quad = lane >> 4, l15 = lane & 15;
  int idx = blockIdx.x;
  int bh = idx & 31;                        // XCD pinning: idx%8 == bh%8
  int g = idx >> 5;                         // 0..31
  int qt = (g < 16) ? (31 - g) : (g - 16);  // bijection; per-CU load uniform
  int q0 = qt * 64;
  int b = bh >> 4, h = bh & 15;
  const bf16* Qb = QKV + (size_t)b * SEQ * QKVW + h * 64;  // row stride QKVW
  const bf16* Kb = Qb + DM;
  const bf16* VTb = VT + (size_t)bh * HDIM * SEQ;          // [d][s]

  // Q B-frag (col=q=l15, k=d=8*quad+i within 32-slice)
  int qg = q0 + wave * 16 + l15;
  const bf16* qr = Qb + (size_t)qg * QKVW;
  bf16x8 qf0 = *(const bf16x8*)(qr + quad * 8);
  bf16x8 qf1 = *(const bf16x8*)(qr + 32 + quad * 8);

  int r0c = tid >> 3, off0 = (tid & 7) * 8;  // staging: row 0..31, off 0..56

  int niter = qt + 1;
  f32x4 oT[4] = {};     // PV acc: col d = dt*16+l15, row q = 4*quad+r
  float lsum = 0.f;

  f32x4 sPrev[4];       // deferred S^T of previous tile
  bf16x8 vpf0[4], vpf1[4];  // sigma-ordered V frags of previous tile (regs)

  bf16x8 kpre0 = *(const bf16x8*)(Kb + (size_t)r0c * QKVW + off0);
  bf16x8 kpre1 = *(const bf16x8*)(Kb + (size_t)(r0c + 32) * QKVW + off0);
  bf16x8 vpre0 = *(const bf16x8*)(VTb + (size_t)r0c * SEQ + off0);
  bf16x8 vpre1 = *(const bf16x8*)(VTb + (size_t)(r0c + 32) * SEQ + off0);

  for (int tkv = 0; tkv < niter; ++tkv) {
    bf16* kb = k_lds[tkv & 1];
    bf16* vb = v_lds[tkv & 1];
    *(bf16x8*)(kb + r0c * 72 + off0) = kpre0;
    *(bf16x8*)(kb + (r0c + 32) * 72 + off0) = kpre1;
    *(bf16x8*)(vb + r0c * 72 + off0) = vpre0;
    *(bf16x8*)(vb + (r0c + 32) * 72 + off0) = vpre1;
    __syncthreads();
    if (tkv + 1 < niter) {
      int kn = tkv * 64 + 64;
      kpre0 = *(const bf16x8*)(Kb + (size_t)(kn + r0c) * QKVW + off0);
      kpre1 = *(const bf16x8*)(Kb + (size_t)(kn + r0c + 32) * QKVW + off0);
      vpre0 = *(const bf16x8*)(VTb + (size_t)r0c * SEQ + kn + off0);
      vpre1 = *(const bf16x8*)(VTb + (size_t)(r0c + 32) * SEQ + kn + off0);
    }
    // QK^T(t) swapped: sCur[nt] = S^T[kv=nt*16+4*quad+r][q=l15]
    f32x4 sCur[4];
    __builtin_amdgcn_s_setprio(1);
#pragma unroll
    for (int nt = 0; nt < 4; ++nt) {
      const bf16* kr = kb + (nt * 16 + l15) * 72;
      bf16x8 kf0 = *(const bf16x8*)(kr + quad * 8);
      bf16x8 kf1 = *(const bf16x8*)(kr + 32 + quad * 8);
      f32x4 z = {};
      z = __builtin_amdgcn_mfma_f32_16x16x32_bf16(kf0, qf0, z, 0, 0, 0);
      z = __builtin_amdgcn_mfma_f32_16x16x32_bf16(kf1, qf1, z, 0, 0, 0);
      sCur[nt] = z;
    }
    __builtin_amdgcn_s_setprio(0);
    if (tkv > 0) {  // finish tile t-1 (interior: no mask)
      float pv[4][4];
#pragma unroll
      for (int nt = 0; nt < 4; ++nt)
#pragma unroll
        for (int r = 0; r < 4; ++r) {
          float p = __builtin_amdgcn_exp2f(sPrev[nt][r] * C2 + C3);
          pv[nt][r] = p;
          lsum += p;
        }
      i32x4 w0 = {pk2(pv[0][0], pv[0][1]), pk2(pv[0][2], pv[0][3]),
                  pk2(pv[1][0], pv[1][1]), pk2(pv[1][2], pv[1][3])};
      i32x4 w1 = {pk2(pv[2][0], pv[2][1]), pk2(pv[2][2], pv[2][3]),
                  pk2(pv[3][0], pv[3][1]), pk2(pv[3][2], pv[3][3])};
      bf16x8 pa0 = __builtin_bit_cast(bf16x8, w0);
      bf16x8 pa1 = __builtin_bit_cast(bf16x8, w1);
      __builtin_amdgcn_s_setprio(1);
#pragma unroll
      for (int dt = 0; dt < 4; ++dt) {
        oT[dt] = __builtin_amdgcn_mfma_f32_16x16x32_bf16(pa0, vpf0[dt], oT[dt], 0, 0, 0);
        oT[dt] = __builtin_amdgcn_mfma_f32_16x16x32_bf16(pa1, vpf1[dt], oT[dt], 0, 0, 0);
      }
      __builtin_amdgcn_s_setprio(0);
    }
    // load V(t) sigma-frags into registers (own-iteration read: race-free)
#pragma unroll
    for (int dt = 0; dt < 4; ++dt) {
      const bf16* vd = vb + (dt * 16 + l15) * 72 + 4 * quad;
      bf16x4 a0 = *(const bf16x4*)(vd);        // kv 4q+0..3
      bf16x4 a1 = *(const bf16x4*)(vd + 16);   // kv 16+4q+0..3
      vpf0[dt] = __builtin_shufflevector(a0, a1, 0, 1, 2, 3, 4, 5, 6, 7);
      bf16x4 b0 = *(const bf16x4*)(vd + 32);   // kv 32+4q+0..3
      bf16x4 b1 = *(const bf16x4*)(vd + 48);   // kv 48+4q+0..3
      vpf1[dt] = __builtin_shufflevector(b0, b1, 0, 1, 2, 3, 4, 5, 6, 7);
    }
    sPrev[0] = sCur[0]; sPrev[1] = sCur[1];
    sPrev[2] = sCur[2]; sPrev[3] = sCur[3];
  }
  {  // final tile (tkv = qt): diagonal, masked finish
    int kv0 = (niter - 1) * 64;
    float pv[4][4];
#pragma unroll
    for (int nt = 0; nt < 4; ++nt)
#pragma unroll
      for (int r = 0; r < 4; ++r) {
        float p = __builtin_amdgcn_exp2f(sPrev[nt][r] * C2 + C3);
        int kvg = kv0 + nt * 16 + 4 * quad + r;
        if (kvg > qg) p = 0.f;
        pv[nt][r] = p;
        lsum += p;
      }
    i32x4 w0 = {pk2(pv[0][0], pv[0][1]), pk2(pv[0][2], pv[0][3]),
                pk2(pv[1][0], pv[1][1]), pk2(pv[1][2], pv[1][3])};
    i32x4 w1 = {pk2(pv[2][0], pv[2][1]), pk2(pv[2][2], pv[2][3]),
                pk2(pv[3][0], pv[3][1]), pk2(pv[3][2], pv[3][3])};
    bf16x8 pa0 = __builtin_bit_cast(bf16x8, w0);
    bf16x8 pa1 = __builtin_bit_cast(bf16x8, w1);
#pragma unroll
    for (int dt = 0; dt < 4; ++dt) {
      oT[dt] = __builtin_amdgcn_mfma_f32_16x16x32_bf16(pa0, vpf0[dt], oT[dt], 0, 0, 0);
      oT[dt] = __builtin_amdgcn_mfma_f32_16x16x32_bf16(pa1, vpf1[dt], oT[dt], 0, 0, 0);
    }
  }
  // denominator: reduce lsum over quads (lanes sharing q=l15: xor16, xor32)
  float t = lsum;
  t += __shfl_xor(t, 16);
  t += __shfl_xor(t, 32);          // all lanes: t = L[q=l15]
  // epilogue: O row q = q0+wave*16+4*quad+r, col d = dt*16+l15
#pragma unroll
  for (int r = 0; r < 4; ++r) {
    float Lr = __shfl(t, 4 * quad + r);   // L for this row's q
    float inv = 1.f / Lr;
    int sq = q0 + wave * 16 + 4 * quad + r;
#pragma unroll
    for (int dt = 0; dt < 4; ++dt)
      O[(size_t)(b * SEQ + sq) * DM + h * HDIM + dt * 16 + l15] =
          (bf16)(oT[dt][r] * inv);
  }
}

extern "C" void kernel_launch(void* const* d_in, const int* in_sizes, int n_in,
                              void* d_out, int out_size, void* d_ws,
                              size_t ws_size, hipStream_t stream) {
  const float* hidden = (const float*)d_in[0];   // [2,2048,1024] f32
  const float* w_qkv  = (const float*)d_in[1];   // [1024,3072]  f32
  const float* w_out  = (const float*)d_in[2];   // [1024,1024]  f32
  const int*   pos    = (const int*)d_in[3];     // [2,2048,3]   i32
  float* out = (float*)d_out;                    // f32 output

  char* ws = (char*)d_ws;
  bf16* wqkvT  = (bf16*)ws;  ws += (size_t)3072 * 1024 * 2;
  bf16* woutT  = (bf16*)ws;  ws += (size_t)1024 * 1024 * 2;
  bf16* hid_bf = (bf16*)ws;  ws += (size_t)4096 * 1024 * 2;
  bf16* qkv_ws = (bf16*)ws;  ws += (size_t)4096 * 3072 * 2;
  bf16* vT_ws  = (bf16*)ws;  ws += (size_t)32 * SEQ * HDIM * 2;
  float2* ropetbl = (float2*)ws;  // 1 MB
  bf16* attn_ws = hid_bf;  // alias: hid_bf dead after gemm_bt

  prep<<<dim3(3584), 256, 0, stream>>>(hidden, w_qkv, w_out, pos,
                                       hid_bf, wqkvT, woutT, ropetbl);
  gemm_bt<<<dim3(24, 32), 256, 0, stream>>>(
      hid_bf, wqkvT, qkv_ws, 4096, 3072, 1024);
  post_qkv<<<dim3(3072), 256, 0, stream>>>(qkv_ws, ropetbl, vT_ws);
  attn_fwd<<<dim3(1024), 256, 0, stream>>>(qkv_ws, vT_ws, attn_ws);
  gemm_bt64<<<dim3(8, 64), 256, 0, stream>>>(
      attn_ws, woutT, out, 4096, 1024, 1024);
}

// Round 13
// 187.920 us; speedup vs baseline: 1.1426x; 1.0365x over previous
//
#include <hip/hip_runtime.h>
#include <hip/hip_bf16.h>
#include <math.h>

typedef __bf16 bf16;
typedef __bf16 bf16x4 __attribute__((ext_vector_type(4)));
typedef __bf16 bf16x8 __attribute__((ext_vector_type(8)));
typedef float f32x4 __attribute__((ext_vector_type(4)));
typedef int i32x4 __attribute__((ext_vector_type(4)));

#define SEQ 2048
#define NHEADS 16
#define HDIM 64
#define DM 1024
#define QKVW 3072

__device__ __forceinline__ void gload_lds16(const void* g, void* l) {
  __builtin_amdgcn_global_load_lds(
      (const __attribute__((address_space(1))) unsigned int*)g,
      (__attribute__((address_space(3))) unsigned int*)l, 16, 0, 0);
}

// pack two f32 -> one dword of 2 bf16 (lo = a, hi = b)
__device__ __forceinline__ int pk2(float a, float b) {
  union { __bf16 h; unsigned short u; } ua, ub;
  ua.h = (__bf16)a; ub.h = (__bf16)b;
  return (int)ua.u | ((int)ub.u << 16);
}

// ---------------- prep: cvt | transpose wqkv | transpose wout | rope table --
__global__ __launch_bounds__(256) void prep(
    const float* __restrict__ hidden, const float* __restrict__ w_qkv,
    const float* __restrict__ w_out, const int* __restrict__ pos,
    bf16* __restrict__ hid_bf, bf16* __restrict__ wqkvT,
    bf16* __restrict__ woutT, float2* __restrict__ tbl) {
  __shared__ float tile[64][65];
  int idx = blockIdx.x, tid = threadIdx.x;
  if (idx < 2048) {  // cvt f32->bf16, 8 elems/thread
    int i = (idx * 256 + tid) * 8;
    float4 a = *(const float4*)(hidden + i);
    float4 b = *(const float4*)(hidden + i + 4);
    bf16x8 o;
    o[0] = (bf16)a.x; o[1] = (bf16)a.y; o[2] = (bf16)a.z; o[3] = (bf16)a.w;
    o[4] = (bf16)b.x; o[5] = (bf16)b.y; o[6] = (bf16)b.z; o[7] = (bf16)b.w;
    *(bf16x8*)(hid_bf + i) = o;
  } else if (idx < 3072) {  // weight transposes f32 -> bf16^T
    const float* in; bf16* out; int R, C, t;
    if (idx < 2816) { t = idx - 2048; in = w_qkv; out = wqkvT; R = 1024; C = 3072; }
    else            { t = idx - 2816; in = w_out; out = woutT; R = 1024; C = 1024; }
    int nbx = C >> 6;
    int c0 = (t % nbx) * 64, r0 = (t / nbx) * 64;
    int col = tid & 63, rb = (tid >> 6) * 16;
#pragma unroll
    for (int i = 0; i < 16; ++i)
      tile[rb + i][col] = in[(size_t)(r0 + rb + i) * C + c0 + col];
    __syncthreads();
#pragma unroll
    for (int i = 0; i < 16; ++i)
      out[(size_t)(c0 + rb + i) * R + r0 + col] = (bf16)tile[col][rb + i];
  } else {  // rope table: tbl[m][pair] = (cos, sin)
    const float LN1E4 = 9.210340371976184f;
    int gi = (idx - 3072) * 256 + tid;  // 4096*32
    int m = gi >> 5, pr = gi & 31;
    int axis, d, iloc;
    if (pr < 10)      { axis = 0; d = 20; iloc = pr; }
    else if (pr < 20) { axis = 1; d = 20; iloc = pr - 10; }
    else              { axis = 2; d = 24; iloc = pr - 20; }
    int p = pos[m * 3 + axis];
    int pmax = (axis == 2) ? 7 : 31;
    p = p < 0 ? 0 : (p > pmax ? pmax : p);
    float invf = __expf(-((float)(2 * iloc) / (float)d) * LN1E4);
    float sn, cs;
    __sincosf((float)p * invf, &sn, &cs);
    tbl[gi] = make_float2(cs, sn);
  }
}

// ---------------- post_qkv: in-place RoPE on Q|K  |  V^T build --------------
__global__ __launch_bounds__(256) void post_qkv(
    bf16* __restrict__ qkv, const float2* __restrict__ tbl,
    bf16* __restrict__ vT) {
  __shared__ bf16 btile[64][65];
  int idx = blockIdx.x, tid = threadIdx.x;
  if (idx < 2048) {  // rope: thread = 16 contiguous elems (8 pairs)
    int gi = idx * 256 + tid;
    int m = gi >> 7, seg = gi & 127;
    bf16* p = qkv + (size_t)m * QKVW + seg * 16;
    bf16x8 a = *(const bf16x8*)p;
    bf16x8 b2 = *(const bf16x8*)(p + 8);
    const float2* t = tbl + m * 32 + (((seg * 16) & 63) >> 1);
#pragma unroll
    for (int j = 0; j < 4; ++j) {
      float2 cs = t[j];
      float e = (float)a[2 * j], o = (float)a[2 * j + 1];
      a[2 * j]     = (bf16)(e * cs.x - o * cs.y);
      a[2 * j + 1] = (bf16)(o * cs.x + e * cs.y);
    }
#pragma unroll
    for (int j = 0; j < 4; ++j) {
      float2 cs = t[4 + j];
      float e = (float)b2[2 * j], o = (float)b2[2 * j + 1];
      b2[2 * j]     = (bf16)(e * cs.x - o * cs.y);
      b2[2 * j + 1] = (bf16)(o * cs.x + e * cs.y);
    }
    *(bf16x8*)p = a;
    *(bf16x8*)(p + 8) = b2;
  } else {  // vT build: [s][d] -> [bh][d][s]
    int t = idx - 2048;
    int s0 = (t & 31) * 64, bh = t >> 5;
    int b = bh >> 4, h = bh & 15;
    const bf16* src = qkv + (size_t)(b * SEQ + s0) * QKVW + 2 * DM + h * 64;
    int col = tid & 63, rb = (tid >> 6) * 16;
#pragma unroll
    for (int i = 0; i < 16; ++i)
      btile[rb + i][col] = src[(size_t)(rb + i) * QKVW + col];
    __syncthreads();
    bf16* dst = vT + (size_t)bh * HDIM * SEQ + s0;
#pragma unroll
    for (int i = 0; i < 16; ++i)
      dst[(size_t)(rb + i) * SEQ + col] = btile[col][rb + i];
  }
}

// ------- GEMM 128x128, BK=64: C(bf16) = A[M,K] * Bt[N,K]^T (R12-verified) ---
__global__ __launch_bounds__(256) void gemm_bt(
    const bf16* __restrict__ A, const bf16* __restrict__ Bt,
    bf16* __restrict__ C, int M, int N, int K) {
  __shared__ __align__(16) bf16 a_lds[2][128 * 32];
  __shared__ __align__(16) bf16 b_lds[2][128 * 32];
  int tid = threadIdx.x;
  int wave = tid >> 6, lane = tid & 63;
  int quad = lane >> 4, l15 = lane & 15;
  int wm = wave >> 1, wn = wave & 1;

  int flat = blockIdx.y * gridDim.x + blockIdx.x;
  int mband = gridDim.y >> 3;
  int xcd = flat & 7, sidx = flat >> 3;
  int m0 = (xcd * mband + (sidx % mband)) * 128;
  int n0 = (sidx / mband) * 128;

  f32x4 acc[4][4] = {};

  for (int kt = 0; kt < K; kt += 64) {
    __syncthreads();
#pragma unroll
    for (int ks = 0; ks < 2; ++ks)
#pragma unroll
      for (int call = 0; call < 2; ++call) {
        int chunk = call * 256 + tid;
        int row = chunk >> 2, cc = (chunk & 3) * 8;
        gload_lds16(A + (size_t)(m0 + row) * K + kt + ks * 32 + cc,
                    (char*)a_lds[ks] + call * 4096 + wave * 1024);
        gload_lds16(Bt + (size_t)(n0 + row) * K + kt + ks * 32 + cc,
                    (char*)b_lds[ks] + call * 4096 + wave * 1024);
      }
    __syncthreads();
    bf16x8 af[2][4], bfr[2][4];
#pragma unroll
    for (int ks = 0; ks < 2; ++ks)
#pragma unroll
      for (int i = 0; i < 4; ++i) {
        af[ks][i]  = *(const bf16x8*)(a_lds[ks] + (wm * 64 + i * 16 + l15) * 32 + quad * 8);
        bfr[ks][i] = *(const bf16x8*)(b_lds[ks] + (wn * 64 + i * 16 + l15) * 32 + quad * 8);
      }
#pragma unroll
    for (int mi = 0; mi < 4; ++mi)
#pragma unroll
      for (int ni = 0; ni < 4; ++ni) {
        acc[mi][ni] = __builtin_amdgcn_mfma_f32_16x16x32_bf16(
            af[0][mi], bfr[0][ni], acc[mi][ni], 0, 0, 0);
        acc[mi][ni] = __builtin_amdgcn_mfma_f32_16x16x32_bf16(
            af[1][mi], bfr[1][ni], acc[mi][ni], 0, 0, 0);
      }
  }

#pragma unroll
  for (int mi = 0; mi < 4; ++mi) {
    int mb = m0 + wm * 64 + mi * 16 + quad * 4;
#pragma unroll
    for (int ni = 0; ni < 4; ++ni) {
      int n = n0 + wn * 64 + ni * 16 + l15;
#pragma unroll
      for (int r = 0; r < 4; ++r)
        C[(size_t)(mb + r) * N + n] = (bf16)acc[mi][ni][r];
    }
  }
}

// ------- GEMM 64x128, BK=64, f32 out (out-projection) -----------------------
// Same BK 32->64 restructuring as gemm_bt (R12-verified mechanism): 16
// K-steps, half the barrier drains, two independent [*][32] LDS sub-buffers
// per operand (per-slice staging/reads byte-identical to the BK=32 pattern).
// LDS 24KB; grid 512 = 2 blocks/CU (cap 6) -- no occupancy change.
__global__ __launch_bounds__(256) void gemm_bt64(
    const bf16* __restrict__ A, const bf16* __restrict__ Bt,
    float* __restrict__ C, int M, int N, int K) {
  __shared__ __align__(16) bf16 a_lds[2][64 * 32];
  __shared__ __align__(16) bf16 b_lds[2][128 * 32];
  int tid = threadIdx.x;
  int wave = tid >> 6, lane = tid & 63;
  int quad = lane >> 4, l15 = lane & 15;
  int wm = wave >> 1, wn = wave & 1;

  int flat = blockIdx.y * gridDim.x + blockIdx.x;
  int mband = gridDim.y >> 3;  // m-tiles (64-row) per XCD band
  int xcd = flat & 7, sidx = flat >> 3;
  int m0 = (xcd * mband + (sidx % mband)) * 64;
  int n0 = (sidx / mband) * 128;

  f32x4 acc[2][4] = {};

  for (int kt = 0; kt < K; kt += 64) {
    __syncthreads();
#pragma unroll
    for (int ks = 0; ks < 2; ++ks) {
      {  // A: 64 rows x 32 = 256 chunks, one per thread
        int row = tid >> 2, cc = (tid & 3) * 8;
        gload_lds16(A + (size_t)(m0 + row) * K + kt + ks * 32 + cc,
                    (char*)a_lds[ks] + wave * 1024);
      }
#pragma unroll
      for (int call = 0; call < 2; ++call) {  // B: 128 rows x 32
        int chunk = call * 256 + tid;
        int row = chunk >> 2, cc = (chunk & 3) * 8;
        gload_lds16(Bt + (size_t)(n0 + row) * K + kt + ks * 32 + cc,
                    (char*)b_lds[ks] + call * 4096 + wave * 1024);
      }
    }
    __syncthreads();
    bf16x8 af[2][2], bfr[2][4];
#pragma unroll
    for (int ks = 0; ks < 2; ++ks) {
#pragma unroll
      for (int i = 0; i < 2; ++i)
        af[ks][i] = *(const bf16x8*)(a_lds[ks] + (wm * 32 + i * 16 + l15) * 32 + quad * 8);
#pragma unroll
      for (int i = 0; i < 4; ++i)
        bfr[ks][i] = *(const bf16x8*)(b_lds[ks] + (wn * 64 + i * 16 + l15) * 32 + quad * 8);
    }
#pragma unroll
    for (int mi = 0; mi < 2; ++mi)
#pragma unroll
      for (int ni = 0; ni < 4; ++ni) {
        acc[mi][ni] = __builtin_amdgcn_mfma_f32_16x16x32_bf16(
            af[0][mi], bfr[0][ni], acc[mi][ni], 0, 0, 0);
        acc[mi][ni] = __builtin_amdgcn_mfma_f32_16x16x32_bf16(
            af[1][mi], bfr[1][ni], acc[mi][ni], 0, 0, 0);
      }
  }

#pragma unroll
  for (int mi = 0; mi < 2; ++mi) {
    int mb = m0 + wm * 32 + mi * 16 + quad * 4;
#pragma unroll
    for (int ni = 0; ni < 4; ++ni) {
      int n = n0 + wn * 64 + ni * 16 + l15;
#pragma unroll
      for (int r = 0; r < 4; ++r)
        C[(size_t)(mb + r) * N + n] = acc[mi][ni][r];
    }
  }
}

// -------- causal flash attention: R8 base + 2-deep pipeline (T15) -----------
// Iter t: QK(t) on MFMA pipe; softmax+pack+PV of tile t-1 overlapped (VALU /
// MFMA). V-fragments are ds_read into REGISTERS in their own iteration (safe
// window, same single-barrier proof as R8); only the PV MFMAs are deferred.
// Interior finishes never need the causal mask (only tile qt is diagonal,
// finished post-loop).
__global__ __launch_bounds__(256, 4) void attn_fwd(
    const bf16* __restrict__ QKV, const bf16* __restrict__ VT,
    bf16* __restrict__ O) {
  __shared__ __align__(16) bf16 k_lds[2][64 * 72];  // [buf][kv][d]
  __shared__ __align__(16) bf16 v_lds[2][64 * 72];  // [buf][d][kv]
  const float C2 = 0.18033688011112042f;   // 0.125 * log2(e)
  const float C3 = -5.770780163555854f;    // -4 * log2(e)
  int tid = threadIdx.x;
  int wave = tid >> 6, lane = tid & 63;
  int quad = lane >> 4, l15 = lane & 15;
  int idx = blockIdx.x;
  int bh = idx & 31;                        // XCD pinning: idx%8 == bh%8
  int g = idx >> 5;                         // 0..31
  int qt = (g < 16) ? (31 - g) : (g - 16);  // bijection; per-CU load uniform
  int q0 = qt * 64;
  int b = bh >> 4, h = bh & 15;
  const bf16* Qb = QKV + (size_t)b * SEQ * QKVW + h * 64;  // row stride QKVW
  const bf16* Kb = Qb + DM;
  const bf16* VTb = VT + (size_t)bh * HDIM * SEQ;          // [d][s]

  // Q B-frag (col=q=l15, k=d=8*quad+i within 32-slice)
  int qg = q0 + wave * 16 + l15;
  const bf16* qr = Qb + (size_t)qg * QKVW;
  bf16x8 qf0 = *(const bf16x8*)(qr + quad * 8);
  bf16x8 qf1 = *(const bf16x8*)(qr + 32 + quad * 8);

  int r0c = tid >> 3, off0 = (tid & 7) * 8;  // staging: row 0..31, off 0..56

  int niter = qt + 1;
  f32x4 oT[4] = {};     // PV acc: col d = dt*16+l15, row q = 4*quad+r
  float lsum = 0.f;

  f32x4 sPrev[4];       // deferred S^T of previous tile
  bf16x8 vpf0[4], vpf1[4];  // sigma-ordered V frags of previous tile (regs)

  bf16x8 kpre0 = *(const bf16x8*)(Kb + (size_t)r0c * QKVW + off0);
  bf16x8 kpre1 = *(const bf16x8*)(Kb + (size_t)(r0c + 32) * QKVW + off0);
  bf16x8 vpre0 = *(const bf16x8*)(VTb + (size_t)r0c * SEQ + off0);
  bf16x8 vpre1 = *(const bf16x8*)(VTb + (size_t)(r0c + 32) * SEQ + off0);

  for (int tkv = 0; tkv < niter; ++tkv) {
    bf16* kb = k_lds[tkv & 1];
    bf16* vb = v_lds[tkv & 1];
    *(bf16x8*)(kb + r0c * 72 + off0) = kpre0;
    *(bf16x8*)(kb + (r0c + 32) * 72 + off0) = kpre1;
    *(bf16x8*)(vb + r0c * 72 + off0) = vpre0;
    *(bf16x8*)(vb + (r0c + 32) * 72 + off0) = vpre1;
    __syncthreads();
    if (tkv + 1 < niter) {
      int kn = tkv * 64 + 64;
      kpre0 = *(const bf16x8*)(Kb + (size_t)(kn + r0c) * QKVW + off0);
      kpre1 = *(const bf16x8*)(Kb + (size_t)(kn + r0c + 32) * QKVW + off0);
      vpre0 = *(const bf16x8*)(VTb + (size_t)r0c * SEQ + kn + off0);
      vpre1 = *(const bf16x8*)(VTb + (size_t)(r0c + 32) * SEQ + kn + off0);
    }
    // QK^T(t) swapped: sCur[nt] = S^T[kv=nt*16+4*quad+r][q=l15]
    f32x4 sCur[4];
    __builtin_amdgcn_s_setprio(1);
#pragma unroll
    for (int nt = 0; nt < 4; ++nt) {
      const bf16* kr = kb + (nt * 16 + l15) * 72;
      bf16x8 kf0 = *(const bf16x8*)(kr + quad * 8);
      bf16x8 kf1 = *(const bf16x8*)(kr + 32 + quad * 8);
      f32x4 z = {};
      z = __builtin_amdgcn_mfma_f32_16x16x32_bf16(kf0, qf0, z, 0, 0, 0);
      z = __builtin_amdgcn_mfma_f32_16x16x32_bf16(kf1, qf1, z, 0, 0, 0);
      sCur[nt] = z;
    }
    __builtin_amdgcn_s_setprio(0);
    if (tkv > 0) {  // finish tile t-1 (interior: no mask)
      float pv[4][4];
#pragma unroll
      for (int nt = 0; nt < 4; ++nt)
#pragma unroll
        for (int r = 0; r < 4; ++r) {
          float p = __builtin_amdgcn_exp2f(sPrev[nt][r] * C2 + C3);
          pv[nt][r] = p;
          lsum += p;
        }
      i32x4 w0 = {pk2(pv[0][0], pv[0][1]), pk2(pv[0][2], pv[0][3]),
                  pk2(pv[1][0], pv[1][1]), pk2(pv[1][2], pv[1][3])};
      i32x4 w1 = {pk2(pv[2][0], pv[2][1]), pk2(pv[2][2], pv[2][3]),
                  pk2(pv[3][0], pv[3][1]), pk2(pv[3][2], pv[3][3])};
      bf16x8 pa0 = __builtin_bit_cast(bf16x8, w0);
      bf16x8 pa1 = __builtin_bit_cast(bf16x8, w1);
      __builtin_amdgcn_s_setprio(1);
#pragma unroll
      for (int dt = 0; dt < 4; ++dt) {
        oT[dt] = __builtin_amdgcn_mfma_f32_16x16x32_bf16(pa0, vpf0[dt], oT[dt], 0, 0, 0);
        oT[dt] = __builtin_amdgcn_mfma_f32_16x16x32_bf16(pa1, vpf1[dt], oT[dt], 0, 0, 0);
      }
      __builtin_amdgcn_s_setprio(0);
    }
    // load V(t) sigma-frags into registers (own-iteration read: race-free)
#pragma unroll
    for (int dt = 0; dt < 4; ++dt) {
      const bf16* vd = vb + (dt * 16 + l15) * 72 + 4 * quad;
      bf16x4 a0 = *(const bf16x4*)(vd);        // kv 4q+0..3
      bf16x4 a1 = *(const bf16x4*)(vd + 16);   // kv 16+4q+0..3
      vpf0[dt] = __builtin_shufflevector(a0, a1, 0, 1, 2, 3, 4, 5, 6, 7);
      bf16x4 b0 = *(const bf16x4*)(vd + 32);   // kv 32+4q+0..3
      bf16x4 b1 = *(const bf16x4*)(vd + 48);   // kv 48+4q+0..3
      vpf1[dt] = __builtin_shufflevector(b0, b1, 0, 1, 2, 3, 4, 5, 6, 7);
    }
    sPrev[0] = sCur[0]; sPrev[1] = sCur[1];
    sPrev[2] = sCur[2]; sPrev[3] = sCur[3];
  }
  {  // final tile (tkv = qt): diagonal, masked finish
    int kv0 = (niter - 1) * 64;
    float pv[4][4];
#pragma unroll
    for (int nt = 0; nt < 4; ++nt)
#pragma unroll
      for (int r = 0; r < 4; ++r) {
        float p = __builtin_amdgcn_exp2f(sPrev[nt][r] * C2 + C3);
        int kvg = kv0 + nt * 16 + 4 * quad + r;
        if (kvg > qg) p = 0.f;
        pv[nt][r] = p;
        lsum += p;
      }
    i32x4 w0 = {pk2(pv[0][0], pv[0][1]), pk2(pv[0][2], pv[0][3]),
                pk2(pv[1][0], pv[1][1]), pk2(pv[1][2], pv[1][3])};
    i32x4 w1 = {pk2(pv[2][0], pv[2][1]), pk2(pv[2][2], pv[2][3]),
                pk2(pv[3][0], pv[3][1]), pk2(pv[3][2], pv[3][3])};
    bf16x8 pa0 = __builtin_bit_cast(bf16x8, w0);
    bf16x8 pa1 = __builtin_bit_cast(bf16x8, w1);
#pragma unroll
    for (int dt = 0; dt < 4; ++dt) {
      oT[dt] = __builtin_amdgcn_mfma_f32_16x16x32_bf16(pa0, vpf0[dt], oT[dt], 0, 0, 0);
      oT[dt] = __builtin_amdgcn_mfma_f32_16x16x32_bf16(pa1, vpf1[dt], oT[dt], 0, 0, 0);
    }
  }
  // denominator: reduce lsum over quads (lanes sharing q=l15: xor16, xor32)
  float t = lsum;
  t += __shfl_xor(t, 16);
  t += __shfl_xor(t, 32);          // all lanes: t = L[q=l15]
  // epilogue: O row q = q0+wave*16+4*quad+r, col d = dt*16+l15
#pragma unroll
  for (int r = 0; r < 4; ++r) {
    float Lr = __shfl(t, 4 * quad + r);   // L for this row's q
    float inv = 1.f / Lr;
    int sq = q0 + wave * 16 + 4 * quad + r;
#pragma unroll
    for (int dt = 0; dt < 4; ++dt)
      O[(size_t)(b * SEQ + sq) * DM + h * HDIM + dt * 16 + l15] =
          (bf16)(oT[dt][r] * inv);
  }
}

extern "C" void kernel_launch(void* const* d_in, const int* in_sizes, int n_in,
                              void* d_out, int out_size, void* d_ws,
                              size_t ws_size, hipStream_t stream) {
  const float* hidden = (const float*)d_in[0];   // [2,2048,1024] f32
  const float* w_qkv  = (const float*)d_in[1];   // [1024,3072]  f32
  const float* w_out  = (const float*)d_in[2];   // [1024,1024]  f32
  const int*   pos    = (const int*)d_in[3];     // [2,2048,3]   i32
  float* out = (float*)d_out;                    // f32 output

  char* ws = (char*)d_ws;
  bf16* wqkvT  = (bf16*)ws;  ws += (size_t)3072 * 1024 * 2;
  bf16* woutT  = (bf16*)ws;  ws += (size_t)1024 * 1024 * 2;
  bf16* hid_bf = (bf16*)ws;  ws += (size_t)4096 * 1024 * 2;
  bf16* qkv_ws = (bf16*)ws;  ws += (size_t)4096 * 3072 * 2;
  bf16* vT_ws  = (bf16*)ws;  ws += (size_t)32 * SEQ * HDIM * 2;
  float2* ropetbl = (float2*)ws;  // 1 MB
  bf16* attn_ws = hid_bf;  // alias: hid_bf dead after gemm_bt

  prep<<<dim3(3584), 256, 0, stream>>>(hidden, w_qkv, w_out, pos,
                                       hid_bf, wqkvT, woutT, ropetbl);
  gemm_bt<<<dim3(24, 32), 256, 0, stream>>>(
      hid_bf, wqkvT, qkv_ws, 4096, 3072, 1024);
  post_qkv<<<dim3(3072), 256, 0, stream>>>(qkv_ws, ropetbl, vT_ws);
  attn_fwd<<<dim3(1024), 256, 0, stream>>>(qkv_ws, vT_ws, attn_ws);
  gemm_bt64<<<dim3(8, 64), 256, 0, stream>>>(
      attn_ws, woutT, out, 4096, 1024, 1024);
}